// Round 5
// baseline (1106.768 us; speedup 1.0000x reference)
//
#include <hip/hip_runtime.h>
#include <hip/hip_bf16.h>
#include <cstdint>
#include <cstddef>

// GCNClassifier on MI355X.
// R11: GEMM occupancy fix. Budget math shows the 512-out GEMMs are ~110-120us
// each (hiding just under the 120us harness fills in top-5) = ~455 TF fp8,
// while the m145 ladder point is ~995 TF. Cause: __launch_bounds__(256,2)
// allows up to 256 VGPR -> 2 blocks/CU -> 8 waves/CU, too little cross-block
// overlap to hide the per-K-step vmcnt(0)+barrier drain (m114 model).
// Fix: __launch_bounds__(256,4) + register-slimmed inner loop (one K-slice
// of fragments at a time: af[4]/bf[4] = ~107 VGPR, fits the 128 cap).
// agg unchanged: it is L2-miss service-rate bound (100KB in flight per CU vs
// ~3.5KB needed), so MLP/unroll changes are null there.

typedef unsigned short u16;
typedef unsigned char u8;
typedef unsigned int u32;
typedef u16 u16x4 __attribute__((ext_vector_type(4)));
typedef u16 u16x8 __attribute__((ext_vector_type(8)));
typedef u32 u32x2 __attribute__((ext_vector_type(2)));
typedef float f32x2 __attribute__((ext_vector_type(2)));
typedef float f32x4 __attribute__((ext_vector_type(4)));

__device__ __forceinline__ u16 f2bf(float f) {
  u32 u = __builtin_bit_cast(u32, f);
  u += 0x7fffu + ((u >> 16) & 1u);   // round-to-nearest-even
  return (u16)(u >> 16);
}
__device__ __forceinline__ float bf2f(u16 h) {
  return __builtin_bit_cast(float, (u32)h << 16);
}
__device__ __forceinline__ void g2lds16(const void* g, void* l) {
  __builtin_amdgcn_global_load_lds((__attribute__((address_space(1))) void*)g,
                                   (__attribute__((address_space(3))) void*)l, 16, 0, 0);
}

// ---------------------------------------------------------------- init / CSR
__global__ __launch_bounds__(256) void init_kernel(int* __restrict__ deg,
                                                   int* __restrict__ cursor,
                                                   float* __restrict__ pool, int N) {
  int i = blockIdx.x * 256 + threadIdx.x;
  if (i < N) { deg[i] = 0; cursor[i] = 0; }
  if (i < 256) pool[i] = 0.f;
}

// Detect int64 vs int32 storage of edge_index.
__global__ void detect_kernel(const int* __restrict__ ei, int* __restrict__ flag) {
  __shared__ int nz;
  if (threadIdx.x == 0) nz = 0;
  __syncthreads();
  if (ei[2 * threadIdx.x + 1] != 0) atomicAdd(&nz, 1);
  __syncthreads();
  if (threadIdx.x == 0) *flag = (nz == 0) ? 1 : 0;
}

__device__ __forceinline__ int ld_src(const int* ei, int E, int e, int f64) {
  return f64 ? (int)((const long long*)ei)[e] : ei[e];
}
__device__ __forceinline__ int ld_dst(const int* ei, int E, int e, int f64) {
  return f64 ? (int)((const long long*)ei)[(long long)E + e] : ei[E + e];
}

__global__ __launch_bounds__(256) void degree_kernel(const int* __restrict__ ei,
                                                     const int* __restrict__ flag,
                                                     int* __restrict__ deg, int E) {
  int e = blockIdx.x * 256 + threadIdx.x;
  if (e >= E) return;
  int f = *flag;
  atomicAdd(&deg[ld_dst(ei, E, e, f)], 1);
}

__global__ __launch_bounds__(256) void dis_kernel(const int* __restrict__ deg,
                                                  float* __restrict__ dis, int N) {
  int i = blockIdx.x * 256 + threadIdx.x;
  if (i < N) dis[i] = rsqrtf((float)deg[i] + 1.0f);
}

__global__ __launch_bounds__(1024) void scan1_kernel(const int* __restrict__ deg,
                                                     int* __restrict__ rs,
                                                     int* __restrict__ bsum, int N) {
  __shared__ int s[1024];
  int tid = threadIdx.x;
  int i = blockIdx.x * 1024 + tid;
  int v = (i < N) ? deg[i] : 0;
  s[tid] = v;
  __syncthreads();
  for (int off = 1; off < 1024; off <<= 1) {
    int t = (tid >= off) ? s[tid - off] : 0;
    __syncthreads();
    s[tid] += t;
    __syncthreads();
  }
  if (i < N) rs[i] = s[tid] - v;        // exclusive
  if (tid == 1023) bsum[blockIdx.x] = s[1023];
}

__global__ __launch_bounds__(1024) void scan2_kernel(const int* __restrict__ bsum,
                                                     int* __restrict__ boff, int nb) {
  __shared__ int s[1024];
  int tid = threadIdx.x;
  int v = (tid < nb) ? bsum[tid] : 0;
  s[tid] = v;
  __syncthreads();
  for (int off = 1; off < 1024; off <<= 1) {
    int t = (tid >= off) ? s[tid - off] : 0;
    __syncthreads();
    s[tid] += t;
    __syncthreads();
  }
  if (tid < nb) boff[tid] = s[tid] - v;  // exclusive
}

__global__ __launch_bounds__(256) void scan3_kernel(int* __restrict__ rs,
                                                    const int* __restrict__ boff, int N) {
  int i = blockIdx.x * 256 + threadIdx.x;
  if (i < N) rs[i] += boff[i >> 10];
}

// fill ev = {src, dis[src]*dis[dst]} per edge (CSR order by dst)
__global__ __launch_bounds__(256) void fill_kernel(const int* __restrict__ ei,
                                                   const int* __restrict__ flag,
                                                   const int* __restrict__ rs,
                                                   int* __restrict__ cursor,
                                                   const float* __restrict__ dis,
                                                   u32x2* __restrict__ ev, int E) {
  int e = blockIdx.x * 256 + threadIdx.x;
  if (e >= E) return;
  int f = *flag;
  int s = ld_src(ei, E, e, f);
  int d = ld_dst(ei, E, e, f);
  int p = atomicAdd(&cursor[d], 1);
  float w = dis[s] * dis[d];
  u32x2 t;
  t.x = (u32)s;
  t.y = __builtin_bit_cast(u32, w);
  ev[rs[d] + p] = t;
}

// ---------------------------------------------------------------- converts
// x fp32 -> fp8, stored swizzled: phys col = col ^ ((row&7)<<3).
__global__ __launch_bounds__(256) void convx_kernel(const float* __restrict__ x,
                                                    u8* __restrict__ x8, size_t n) {
  size_t i = ((size_t)blockIdx.x * 256 + threadIdx.x) * 4;
  if (i >= n) return;
  float4 v = *reinterpret_cast<const float4*>(x + i);
  int lo = __builtin_amdgcn_cvt_pk_fp8_f32(v.x, v.y, 0, false);
  int r = __builtin_amdgcn_cvt_pk_fp8_f32(v.z, v.w, lo, true);
  size_t row = i >> 9;
  int col = (int)(i & 511);
  int sw = ((int)(row & 7)) << 3;
  *reinterpret_cast<u32*>(x8 + row * 512 + (col ^ sw)) = (u32)r;
}

// W[k][n] fp32 -> Wt[n][k] fp8, stored swizzled (row = n).
__global__ __launch_bounds__(256) void convw_kernel(const float* __restrict__ W,
                                                    u8* __restrict__ Wt, int Nout) {
  int id = blockIdx.x * 256 + threadIdx.x;
  if (id >= 512 * Nout) return;
  int k = id / Nout, nn = id - k * Nout;
  float v = W[id];
  int e = __builtin_amdgcn_cvt_pk_fp8_f32(v, v, 0, false);
  Wt[nn * 512 + (k ^ ((nn & 7) << 3))] = (u8)e;
}

// ---------------------------------------------------------------- GEMM (fp8)
// C[M][Nout] = A[M][512] @ W. A, Bt physically swizzled fp8 inputs. 128x128
// tile, BK=64, 4 waves 2x2, LDS reads XOR-swizzled. One K-slice of fragments
// live at a time (af[4]/bf[4]) to keep VGPR <=128 for the (256,4) bound ->
// 4 blocks/CU, cross-block overlap hides the per-step barrier drain.
// Grid 1D XCD-grouped. Output fp8, linear rows.
__global__ __launch_bounds__(256, 4)
void gemm8_kernel(const u8* __restrict__ A, const u8* __restrict__ Bt,
                  u8* __restrict__ Cout, int M, int Nout, int gm, int lgy) {
  const int id = blockIdx.x;
  const int xcd = id & 7, q = id >> 3;
  const int by = q & ((1 << lgy) - 1);
  const int bx = ((q >> lgy) << 3) + xcd;
  if (bx >= gm) return;

  __shared__ u8 sA[128 * 64];  // [row][64] physical (pre-swizzled in global)
  __shared__ u8 sB[128 * 64];
  const int tid = threadIdx.x;
  const int wave = tid >> 6, lane = tid & 63;
  const int m0 = bx * 128;
  const int n0 = by * 128;
  const int wm = (wave >> 1) * 64, wn = (wave & 1) * 64;
  const int srow = tid >> 2;            // 0..63: staging row within 64-row half
  const int soff = (tid & 3) * 16;      // 16B chunk within 64B row
  const int fr = lane & 15, fq8 = (lane >> 4) * 8;
  const int xa = (fr & 7) << 3;         // read-side swizzle for this lane's rows

  f32x4 acc[4][4];
#pragma unroll
  for (int i = 0; i < 4; ++i)
#pragma unroll
    for (int j = 0; j < 4; ++j) acc[i][j] = (f32x4){0.f, 0.f, 0.f, 0.f};

  int ar0 = m0 + srow;      if (ar0 >= M) ar0 = M - 1;  // clamp; never stored
  int ar1 = m0 + 64 + srow; if (ar1 >= M) ar1 = M - 1;
  const size_t a0 = (size_t)ar0 * 512 + soff;
  const size_t a1 = (size_t)ar1 * 512 + soff;
  const size_t b0 = (size_t)(n0 + srow) * 512 + soff;
  const size_t b1 = (size_t)(n0 + 64 + srow) * 512 + soff;

  for (int k0 = 0; k0 < 512; k0 += 64) {
    g2lds16(A + a0 + k0, &sA[wave * 1024]);
    g2lds16(A + a1 + k0, &sA[4096 + wave * 1024]);
    g2lds16(Bt + b0 + k0, &sB[wave * 1024]);
    g2lds16(Bt + b1 + k0, &sB[4096 + wave * 1024]);
    __builtin_amdgcn_s_waitcnt(0);
    __syncthreads();

#pragma unroll
    for (int s = 0; s < 2; ++s) {
      long long af[4], bf[4];
#pragma unroll
      for (int t = 0; t < 4; ++t) {
        const int ra = (wm + t * 16 + fr) * 64;
        const int rb = (wn + t * 16 + fr) * 64;
        af[t] = *reinterpret_cast<const long long*>(&sA[ra + ((s * 32 + fq8) ^ xa)]);
        bf[t] = *reinterpret_cast<const long long*>(&sB[rb + ((s * 32 + fq8) ^ xa)]);
      }
#pragma unroll
      for (int i = 0; i < 4; ++i)
#pragma unroll
        for (int j = 0; j < 4; ++j)
          acc[i][j] = __builtin_amdgcn_mfma_f32_16x16x32_fp8_fp8(af[i], bf[j], acc[i][j], 0, 0, 0);
    }
    __syncthreads();
  }

  // C/D layout: col = lane&15, row = (lane>>4)*4 + reg; store LINEAR.
  const int crow0 = m0 + wm + ((lane >> 4) << 2);
  const int ccol0 = n0 + wn + (lane & 15);
#pragma unroll
  for (int j = 0; j < 4; ++j) {
    const int col = ccol0 + j * 16;
#pragma unroll
    for (int i = 0; i < 4; ++i)
#pragma unroll
      for (int r = 0; r < 4; ++r) {
        int row = crow0 + i * 16 + r;
        if (row < M) {
          float v = acc[i][j][r];
          int e = __builtin_amdgcn_cvt_pk_fp8_f32(v, v, 0, false);
          Cout[(size_t)row * Nout + col] = (u8)e;
        }
      }
  }
}

// ---------------------------------------------------------------- aggregate
// One wave per node, LINEAR fp8 512B rows (8B/lane). Batched index fetch via
// ev (no dis gathers), readlane broadcast, 8 independent row gathers per
// iter. Bias+leaky, 8B-swizzled fp8 out (feeds GEMM staging).
__global__ __launch_bounds__(256)
void agg_kernel(const u8* __restrict__ xw, const u32x2* __restrict__ ev,
                const int* __restrict__ rs, const int* __restrict__ deg,
                const float* __restrict__ dis, const float* __restrict__ bias,
                u8* __restrict__ hout, int N) {
  const int wave = threadIdx.x >> 6;
  const int lane = threadIdx.x & 63;
  const int node = blockIdx.x * 4 + wave;
  if (node >= N) return;
  const int start = rs[node];
  const int d = deg[node];
  const float dd = dis[node];
  const int fo = lane * 8;   // byte offset within 512B row

  f32x2 acc[4];
#pragma unroll
  for (int i = 0; i < 4; ++i) acc[i] = (f32x2){0.f, 0.f};

  const int total = d + 1;                      // edges + self loop
  for (int base = 0; base < total; base += 64) {
    int t = base + lane;
    int s = node;
    float w = 0.f;
    if (t < d)       { u32x2 e = ev[start + t]; s = (int)e.x; w = __builtin_bit_cast(float, e.y); }
    else if (t == d) { w = dd * dd; }           // self loop
    int cnt = total - base;
    if (cnt > 64) cnt = 64;
    int cnt8 = (cnt + 7) & ~7;
    int wi = __builtin_bit_cast(int, w);
    for (int j = 0; j < cnt8; j += 8) {
      u32x2 v[8];
      float ws[8];
#pragma unroll
      for (int k = 0; k < 8; ++k) {
        int sk = __builtin_amdgcn_readlane(s, j + k);
        ws[k] = __builtin_bit_cast(float, __builtin_amdgcn_readlane(wi, j + k));
        v[k] = *reinterpret_cast<const u32x2*>(xw + (size_t)sk * 512 + fo);
      }
#pragma unroll
      for (int k = 0; k < 8; ++k) {
        f32x2 p0 = __builtin_amdgcn_cvt_pk_f32_fp8((int)v[k].x, false);
        f32x2 p1 = __builtin_amdgcn_cvt_pk_f32_fp8((int)v[k].x, true);
        f32x2 p2 = __builtin_amdgcn_cvt_pk_f32_fp8((int)v[k].y, false);
        f32x2 p3 = __builtin_amdgcn_cvt_pk_f32_fp8((int)v[k].y, true);
        f32x2 wv = (f32x2){ws[k], ws[k]};
        acc[0] += wv * p0;
        acc[1] += wv * p1;
        acc[2] += wv * p2;
        acc[3] += wv * p3;
      }
    }
  }

  float h[8];
#pragma unroll
  for (int i = 0; i < 8; ++i) {
    float v = (i & 1) ? acc[i >> 1].y : acc[i >> 1].x;
    v += bias[fo + i];
    v = v >= 0.f ? v : 0.01f * v;
    h[i] = v;
  }
  int lo = __builtin_amdgcn_cvt_pk_fp8_f32(h[0], h[1], 0, false);
  lo = __builtin_amdgcn_cvt_pk_fp8_f32(h[2], h[3], lo, true);
  int hi = __builtin_amdgcn_cvt_pk_fp8_f32(h[4], h[5], 0, false);
  hi = __builtin_amdgcn_cvt_pk_fp8_f32(h[6], h[7], hi, true);
  u32x2 o; o.x = (u32)lo; o.y = (u32)hi;
  __builtin_nontemporal_store(o, reinterpret_cast<u32x2*>(
      hout + (size_t)node * 512 + (fo ^ ((node & 7) << 3))));
}

// L4 aggregate: LINEAR fp8 256B rows (4B/lane), ev stream, bias + leaky,
// bf16 LINEAR output (feeds pool).
__global__ __launch_bounds__(256)
void agg256_kernel(const u8* __restrict__ xw, const u32x2* __restrict__ ev,
                   const int* __restrict__ rs, const int* __restrict__ deg,
                   const float* __restrict__ dis, const float* __restrict__ bias,
                   u16* __restrict__ hout, int N) {
  const int wave = threadIdx.x >> 6;
  const int lane = threadIdx.x & 63;
  const int node = blockIdx.x * 4 + wave;
  if (node >= N) return;
  const int start = rs[node];
  const int d = deg[node];
  const float dd = dis[node];
  const int fo = lane * 4;   // byte offset within 256B row

  f32x2 acc[2];
  acc[0] = (f32x2){0.f, 0.f};
  acc[1] = (f32x2){0.f, 0.f};

  const int total = d + 1;
  for (int base = 0; base < total; base += 64) {
    int t = base + lane;
    int s = node;
    float w = 0.f;
    if (t < d)       { u32x2 e = ev[start + t]; s = (int)e.x; w = __builtin_bit_cast(float, e.y); }
    else if (t == d) { w = dd * dd; }
    int cnt = total - base;
    if (cnt > 64) cnt = 64;
    int cnt8 = (cnt + 7) & ~7;
    int wi = __builtin_bit_cast(int, w);
    for (int j = 0; j < cnt8; j += 8) {
      u32 v[8];
      float ws[8];
#pragma unroll
      for (int k = 0; k < 8; ++k) {
        int sk = __builtin_amdgcn_readlane(s, j + k);
        ws[k] = __builtin_bit_cast(float, __builtin_amdgcn_readlane(wi, j + k));
        v[k] = *reinterpret_cast<const u32*>(xw + (size_t)sk * 256 + fo);
      }
#pragma unroll
      for (int k = 0; k < 8; ++k) {
        f32x2 p0 = __builtin_amdgcn_cvt_pk_f32_fp8((int)v[k], false);
        f32x2 p1 = __builtin_amdgcn_cvt_pk_f32_fp8((int)v[k], true);
        f32x2 wv = (f32x2){ws[k], ws[k]};
        acc[0] += wv * p0;
        acc[1] += wv * p1;
      }
    }
  }

  u16x4 o;
#pragma unroll
  for (int i = 0; i < 4; ++i) {
    float v = (i & 1) ? acc[i >> 1].y : acc[i >> 1].x;
    v += bias[fo + i];
    v = v >= 0.f ? v : 0.01f * v;
    o[i] = f2bf(v);
  }
  *reinterpret_cast<u16x4*>(hout + (size_t)node * 256 + fo) = o;
}

// ---------------------------------------------------------------- pool + FC
__global__ __launch_bounds__(256) void pool_kernel(const u16* __restrict__ h,
                                                   float* __restrict__ pool, int N) {
  __shared__ float lds[8 * 256];
  const int tid = threadIdx.x;
  const int fg = tid & 31;
  const int rg = tid >> 5;
  float acc[8];
#pragma unroll
  for (int i = 0; i < 8; ++i) acc[i] = 0.f;
  for (int r = blockIdx.x * 8 + rg; r < N; r += gridDim.x * 8) {
    u16x8 v = *reinterpret_cast<const u16x8*>(h + (size_t)r * 256 + fg * 8);
#pragma unroll
    for (int i = 0; i < 8; ++i) acc[i] += bf2f(v[i]);
  }
#pragma unroll
  for (int i = 0; i < 8; ++i) lds[rg * 256 + fg * 8 + i] = acc[i];
  __syncthreads();
  float s = 0.f;
#pragma unroll
  for (int g = 0; g < 8; ++g) s += lds[g * 256 + tid];
  atomicAdd(&pool[tid], s);
}

__global__ void fc_kernel(const float* __restrict__ pool, const float* __restrict__ fcW1,
                          const float* __restrict__ fcb1, const float* __restrict__ fcW2,
                          const float* __restrict__ fcb2, float* __restrict__ out,
                          float invN) {
  int j = threadIdx.x;  // 64 threads = 1 wave
  float acc = 0.f;
  for (int f = 0; f < 256; ++f) acc += pool[f] * invN * fcW1[f * 64 + j];
  float h = acc + fcb1[j];
  h = h >= 0.f ? h : 0.01f * h;
  float p = h * fcW2[j];
  for (int o = 32; o; o >>= 1) p += __shfl_down(p, o);
  if (j == 0) out[0] = 1.f / (1.f + expf(-(p + fcb2[0])));
}

// ---------------------------------------------------------------- launch
extern "C" void kernel_launch(void* const* d_in, const int* in_sizes, int n_in,
                              void* d_out, int out_size, void* d_ws, size_t ws_size,
                              hipStream_t stream) {
  const float* x    = (const float*)d_in[0];
  const int*   ei   = (const int*)d_in[1];
  const float* W1   = (const float*)d_in[2];
  const float* b1   = (const float*)d_in[3];
  const float* W2   = (const float*)d_in[4];
  const float* b2   = (const float*)d_in[5];
  const float* W3   = (const float*)d_in[6];
  const float* b3   = (const float*)d_in[7];
  const float* W4   = (const float*)d_in[8];
  const float* b4   = (const float*)d_in[9];
  const float* fcW1 = (const float*)d_in[10];
  const float* fcb1 = (const float*)d_in[11];
  const float* fcW2 = (const float*)d_in[12];
  const float* fcb2 = (const float*)d_in[13];
  float* out = (float*)d_out;

  const int N = in_sizes[0] / 512;
  const int E = in_sizes[1] / 2;

  char* p = (char*)d_ws;
  auto carve = [&](size_t bytes) {
    char* r = p;
    p += (bytes + 255) & ~(size_t)255;
    return r;
  };
  u8*  bufX = (u8*)carve((size_t)N * 512);       // fp8: x8 (swz); h2 (swz)
  u8*  bufP = (u8*)carve((size_t)N * 512);       // fp8: xw per layer (linear)
  u8*  bufQ = (u8*)carve((size_t)N * 512);       // fp8: h1; h3 (swz)
  u16* bufH4 = (u16*)carve((size_t)N * 256 * 2); // bf16 linear h4 for pool
  u8* Wt1 = (u8*)carve(512 * 512);
  u8* Wt2 = (u8*)carve(512 * 512);
  u8* Wt3 = (u8*)carve(512 * 512);
  u8* Wt4 = (u8*)carve(512 * 256);
  int* deg    = (int*)carve((size_t)N * 4);
  int* cursor = (int*)carve((size_t)N * 4);
  int* rs     = (int*)carve((size_t)(N + 1) * 4);
  u32x2* ev   = (u32x2*)carve((size_t)E * 8);
  int* bsum   = (int*)carve(1024 * 4);
  int* boff   = (int*)carve(1024 * 4);
  int* flag   = (int*)carve(256);
  float* disv = (float*)carve((size_t)N * 4);
  float* pool = (float*)carve(256 * 4);
  if ((size_t)(p - (char*)d_ws) > ws_size) return;  // need ~240 MB

  const int nb1024 = (N + 1023) / 1024;

  init_kernel<<<(N + 255) / 256, 256, 0, stream>>>(deg, cursor, pool, N);
  detect_kernel<<<1, 256, 0, stream>>>(ei, flag);
  degree_kernel<<<(E + 255) / 256, 256, 0, stream>>>(ei, flag, deg, E);
  dis_kernel<<<(N + 255) / 256, 256, 0, stream>>>(deg, disv, N);
  scan1_kernel<<<nb1024, 1024, 0, stream>>>(deg, rs, bsum, N);
  scan2_kernel<<<1, 1024, 0, stream>>>(bsum, boff, nb1024);
  scan3_kernel<<<(N + 255) / 256, 256, 0, stream>>>(rs, boff, N);
  fill_kernel<<<(E + 255) / 256, 256, 0, stream>>>(ei, flag, rs, cursor, disv, ev, E);

  convx_kernel<<<((size_t)N * 512 / 4 + 255) / 256, 256, 0, stream>>>(x, bufX, (size_t)N * 512);
  convw_kernel<<<(512 * 512 + 255) / 256, 256, 0, stream>>>(W1, Wt1, 512);
  convw_kernel<<<(512 * 512 + 255) / 256, 256, 0, stream>>>(W2, Wt2, 512);
  convw_kernel<<<(512 * 512 + 255) / 256, 256, 0, stream>>>(W3, Wt3, 512);
  convw_kernel<<<(512 * 256 + 255) / 256, 256, 0, stream>>>(W4, Wt4, 256);

  const int gm = (N + 127) / 128;
  const int gm8 = (gm + 7) & ~7;
  const unsigned ga = (unsigned)((N + 3) / 4);

  // L1: xw1 = x8@W1 ; h1 = leaky(agg xw1 + b1)
  gemm8_kernel<<<gm8 * 4, 256, 0, stream>>>(bufX, Wt1, bufP, N, 512, gm, 2);
  agg_kernel<<<ga, 256, 0, stream>>>(bufP, ev, rs, deg, disv, b1, bufQ, N);
  // L2
  gemm8_kernel<<<gm8 * 4, 256, 0, stream>>>(bufQ, Wt2, bufP, N, 512, gm, 2);
  agg_kernel<<<ga, 256, 0, stream>>>(bufP, ev, rs, deg, disv, b2, bufX, N);
  // L3
  gemm8_kernel<<<gm8 * 4, 256, 0, stream>>>(bufX, Wt3, bufP, N, 512, gm, 2);
  agg_kernel<<<ga, 256, 0, stream>>>(bufP, ev, rs, deg, disv, b3, bufQ, N);
  // L4 (linearity): xw4 = h3@W4 (256-wide fp8 linear) ; h4 = leaky(agg xw4 + b4)
  gemm8_kernel<<<gm8 * 2, 256, 0, stream>>>(bufQ, Wt4, bufP, N, 256, gm, 1);
  agg256_kernel<<<ga, 256, 0, stream>>>(bufP, ev, rs, deg, disv, b4, bufH4, N);

  pool_kernel<<<256, 256, 0, stream>>>(bufH4, pool, N);
  fc_kernel<<<1, 64, 0, stream>>>(pool, fcW1, fcb1, fcW2, fcb2, out, 1.0f / (float)N);
}

// Round 6
// 1094.033 us; speedup vs baseline: 1.0116x; 1.0116x over previous
//
#include <hip/hip_runtime.h>
#include <hip/hip_bf16.h>
#include <cstdint>
#include <cstddef>

// GCNClassifier on MI355X.
// R12: GEMM K-loop restructured to the 2-phase double-buffered schedule
// (T3-minimum recipe). Old: STAGE -> vmcnt(0)+barrier -> compute -> barrier
// exposes full global->LDS latency every K-step (~900 stall cycles of ~1414
// per step at K=512's 8 steps; why R11's occupancy bump was null). New:
// STAGE(next) issued BEFORE compute(cur); the barrier's implicit vmcnt(0)
// drain then lands after ~512 MFMA cycles have absorbed the latency.
// LDS 32KB/block (2x dbuf), __launch_bounds__(256,3). agg untouched
// (L2-miss service-rate bound at ~118us).

typedef unsigned short u16;
typedef unsigned char u8;
typedef unsigned int u32;
typedef u16 u16x4 __attribute__((ext_vector_type(4)));
typedef u16 u16x8 __attribute__((ext_vector_type(8)));
typedef u32 u32x2 __attribute__((ext_vector_type(2)));
typedef float f32x2 __attribute__((ext_vector_type(2)));
typedef float f32x4 __attribute__((ext_vector_type(4)));

__device__ __forceinline__ u16 f2bf(float f) {
  u32 u = __builtin_bit_cast(u32, f);
  u += 0x7fffu + ((u >> 16) & 1u);   // round-to-nearest-even
  return (u16)(u >> 16);
}
__device__ __forceinline__ float bf2f(u16 h) {
  return __builtin_bit_cast(float, (u32)h << 16);
}
__device__ __forceinline__ void g2lds16(const void* g, void* l) {
  __builtin_amdgcn_global_load_lds((__attribute__((address_space(1))) void*)g,
                                   (__attribute__((address_space(3))) void*)l, 16, 0, 0);
}

// ---------------------------------------------------------------- init / CSR
__global__ __launch_bounds__(256) void init_kernel(int* __restrict__ deg,
                                                   int* __restrict__ cursor,
                                                   float* __restrict__ pool, int N) {
  int i = blockIdx.x * 256 + threadIdx.x;
  if (i < N) { deg[i] = 0; cursor[i] = 0; }
  if (i < 256) pool[i] = 0.f;
}

// Detect int64 vs int32 storage of edge_index.
__global__ void detect_kernel(const int* __restrict__ ei, int* __restrict__ flag) {
  __shared__ int nz;
  if (threadIdx.x == 0) nz = 0;
  __syncthreads();
  if (ei[2 * threadIdx.x + 1] != 0) atomicAdd(&nz, 1);
  __syncthreads();
  if (threadIdx.x == 0) *flag = (nz == 0) ? 1 : 0;
}

__device__ __forceinline__ int ld_src(const int* ei, int E, int e, int f64) {
  return f64 ? (int)((const long long*)ei)[e] : ei[e];
}
__device__ __forceinline__ int ld_dst(const int* ei, int E, int e, int f64) {
  return f64 ? (int)((const long long*)ei)[(long long)E + e] : ei[E + e];
}

__global__ __launch_bounds__(256) void degree_kernel(const int* __restrict__ ei,
                                                     const int* __restrict__ flag,
                                                     int* __restrict__ deg, int E) {
  int e = blockIdx.x * 256 + threadIdx.x;
  if (e >= E) return;
  int f = *flag;
  atomicAdd(&deg[ld_dst(ei, E, e, f)], 1);
}

__global__ __launch_bounds__(256) void dis_kernel(const int* __restrict__ deg,
                                                  float* __restrict__ dis, int N) {
  int i = blockIdx.x * 256 + threadIdx.x;
  if (i < N) dis[i] = rsqrtf((float)deg[i] + 1.0f);
}

__global__ __launch_bounds__(1024) void scan1_kernel(const int* __restrict__ deg,
                                                     int* __restrict__ rs,
                                                     int* __restrict__ bsum, int N) {
  __shared__ int s[1024];
  int tid = threadIdx.x;
  int i = blockIdx.x * 1024 + tid;
  int v = (i < N) ? deg[i] : 0;
  s[tid] = v;
  __syncthreads();
  for (int off = 1; off < 1024; off <<= 1) {
    int t = (tid >= off) ? s[tid - off] : 0;
    __syncthreads();
    s[tid] += t;
    __syncthreads();
  }
  if (i < N) rs[i] = s[tid] - v;        // exclusive
  if (tid == 1023) bsum[blockIdx.x] = s[1023];
}

__global__ __launch_bounds__(1024) void scan2_kernel(const int* __restrict__ bsum,
                                                     int* __restrict__ boff, int nb) {
  __shared__ int s[1024];
  int tid = threadIdx.x;
  int v = (tid < nb) ? bsum[tid] : 0;
  s[tid] = v;
  __syncthreads();
  for (int off = 1; off < 1024; off <<= 1) {
    int t = (tid >= off) ? s[tid - off] : 0;
    __syncthreads();
    s[tid] += t;
    __syncthreads();
  }
  if (tid < nb) boff[tid] = s[tid] - v;  // exclusive
}

__global__ __launch_bounds__(256) void scan3_kernel(int* __restrict__ rs,
                                                    const int* __restrict__ boff, int N) {
  int i = blockIdx.x * 256 + threadIdx.x;
  if (i < N) rs[i] += boff[i >> 10];
}

// fill ev = {src, dis[src]*dis[dst]} per edge (CSR order by dst)
__global__ __launch_bounds__(256) void fill_kernel(const int* __restrict__ ei,
                                                   const int* __restrict__ flag,
                                                   const int* __restrict__ rs,
                                                   int* __restrict__ cursor,
                                                   const float* __restrict__ dis,
                                                   u32x2* __restrict__ ev, int E) {
  int e = blockIdx.x * 256 + threadIdx.x;
  if (e >= E) return;
  int f = *flag;
  int s = ld_src(ei, E, e, f);
  int d = ld_dst(ei, E, e, f);
  int p = atomicAdd(&cursor[d], 1);
  float w = dis[s] * dis[d];
  u32x2 t;
  t.x = (u32)s;
  t.y = __builtin_bit_cast(u32, w);
  ev[rs[d] + p] = t;
}

// ---------------------------------------------------------------- converts
// x fp32 -> fp8, stored swizzled: phys col = col ^ ((row&7)<<3).
__global__ __launch_bounds__(256) void convx_kernel(const float* __restrict__ x,
                                                    u8* __restrict__ x8, size_t n) {
  size_t i = ((size_t)blockIdx.x * 256 + threadIdx.x) * 4;
  if (i >= n) return;
  float4 v = *reinterpret_cast<const float4*>(x + i);
  int lo = __builtin_amdgcn_cvt_pk_fp8_f32(v.x, v.y, 0, false);
  int r = __builtin_amdgcn_cvt_pk_fp8_f32(v.z, v.w, lo, true);
  size_t row = i >> 9;
  int col = (int)(i & 511);
  int sw = ((int)(row & 7)) << 3;
  *reinterpret_cast<u32*>(x8 + row * 512 + (col ^ sw)) = (u32)r;
}

// W[k][n] fp32 -> Wt[n][k] fp8, stored swizzled (row = n).
__global__ __launch_bounds__(256) void convw_kernel(const float* __restrict__ W,
                                                    u8* __restrict__ Wt, int Nout) {
  int id = blockIdx.x * 256 + threadIdx.x;
  if (id >= 512 * Nout) return;
  int k = id / Nout, nn = id - k * Nout;
  float v = W[id];
  int e = __builtin_amdgcn_cvt_pk_fp8_f32(v, v, 0, false);
  Wt[nn * 512 + (k ^ ((nn & 7) << 3))] = (u8)e;
}

// ---------------------------------------------------------------- GEMM (fp8)
// C[M][Nout] = A[M][512] @ W. A, Bt physically swizzled fp8 inputs.
// 128x128 tile, BK=64, 4 waves 2x2, LDS reads XOR-swizzled.
// 2-phase double-buffered K-loop: STAGE(next buf) issued BEFORE compute of
// current buf; single barrier per step whose implicit vmcnt(0) drain lands
// after the MFMA cluster. LDS layout: A0@0 A1@8K B0@16K B1@24K.
// Grid 1D XCD-grouped. Output fp8, linear rows.
__global__ __launch_bounds__(256, 3)
void gemm8_kernel(const u8* __restrict__ A, const u8* __restrict__ Bt,
                  u8* __restrict__ Cout, int M, int Nout, int gm, int lgy) {
  const int id = blockIdx.x;
  const int xcd = id & 7, q = id >> 3;
  const int by = q & ((1 << lgy) - 1);
  const int bx = ((q >> lgy) << 3) + xcd;
  if (bx >= gm) return;

  __shared__ u8 smem[32768];   // A0,A1,B0,B1 each 8192B (128 rows x 64B)
  const int tid = threadIdx.x;
  const int wave = tid >> 6, lane = tid & 63;
  const int m0 = bx * 128;
  const int n0 = by * 128;
  const int wm = (wave >> 1) * 64, wn = (wave & 1) * 64;
  const int soff = (tid & 3) * 16;      // 16B chunk within 64B row
  const int fr = lane & 15, fq8 = (lane >> 4) * 8;
  const int xa = (fr & 7) << 3;         // read-side swizzle for this lane's rows

  f32x4 acc[4][4];
#pragma unroll
  for (int i = 0; i < 4; ++i)
#pragma unroll
    for (int j = 0; j < 4; ++j) acc[i][j] = (f32x4){0.f, 0.f, 0.f, 0.f};

  const int srow = tid >> 2;            // 0..63: staging row within 64-row half
  int ar0 = m0 + srow;      if (ar0 >= M) ar0 = M - 1;  // clamp; never stored
  int ar1 = m0 + 64 + srow; if (ar1 >= M) ar1 = M - 1;
  const size_t a0 = (size_t)ar0 * 512 + soff;
  const size_t a1 = (size_t)ar1 * 512 + soff;
  const size_t b0 = (size_t)(n0 + srow) * 512 + soff;
  const size_t b1 = (size_t)(n0 + 64 + srow) * 512 + soff;
  const int wofs = wave * 1024;

  // prologue: stage K-step 0 into buf 0
  {
    g2lds16(A + a0, &smem[wofs]);
    g2lds16(A + a1, &smem[4096 + wofs]);
    g2lds16(Bt + b0, &smem[16384 + wofs]);
    g2lds16(Bt + b1, &smem[16384 + 4096 + wofs]);
  }
  __builtin_amdgcn_s_waitcnt(0);
  __syncthreads();

  int cur = 0;
  for (int t = 0; t < 8; ++t) {
    // issue prefetch of K-step t+1 into the other buffer (before compute)
    if (t < 7) {
      const int k1 = (t + 1) * 64;
      const int nb = (cur ^ 1) * 8192;
      g2lds16(A + a0 + k1, &smem[nb + wofs]);
      g2lds16(A + a1 + k1, &smem[nb + 4096 + wofs]);
      g2lds16(Bt + b0 + k1, &smem[16384 + nb + wofs]);
      g2lds16(Bt + b1 + k1, &smem[16384 + nb + 4096 + wofs]);
    }

    // compute on buf cur
    const u8* sA = &smem[cur * 8192];
    const u8* sB = &smem[16384 + cur * 8192];
#pragma unroll
    for (int s = 0; s < 2; ++s) {
      long long af[4], bf[4];
#pragma unroll
      for (int t4 = 0; t4 < 4; ++t4) {
        const int ra = (wm + t4 * 16 + fr) * 64;
        const int rb = (wn + t4 * 16 + fr) * 64;
        af[t4] = *reinterpret_cast<const long long*>(&sA[ra + ((s * 32 + fq8) ^ xa)]);
        bf[t4] = *reinterpret_cast<const long long*>(&sB[rb + ((s * 32 + fq8) ^ xa)]);
      }
#pragma unroll
      for (int i = 0; i < 4; ++i)
#pragma unroll
        for (int j = 0; j < 4; ++j)
          acc[i][j] = __builtin_amdgcn_mfma_f32_16x16x32_fp8_fp8(af[i], bf[j], acc[i][j], 0, 0, 0);
    }

    // drain prefetch (latency already absorbed by the MFMA cluster) + flip
    __builtin_amdgcn_s_waitcnt(0);
    __syncthreads();
    cur ^= 1;
  }

  // C/D layout: col = lane&15, row = (lane>>4)*4 + reg; store LINEAR.
  const int crow0 = m0 + wm + ((lane >> 4) << 2);
  const int ccol0 = n0 + wn + (lane & 15);
#pragma unroll
  for (int j = 0; j < 4; ++j) {
    const int col = ccol0 + j * 16;
#pragma unroll
    for (int i = 0; i < 4; ++i)
#pragma unroll
      for (int r = 0; r < 4; ++r) {
        int row = crow0 + i * 16 + r;
        if (row < M) {
          float v = acc[i][j][r];
          int e = __builtin_amdgcn_cvt_pk_fp8_f32(v, v, 0, false);
          Cout[(size_t)row * Nout + col] = (u8)e;
        }
      }
  }
}

// ---------------------------------------------------------------- aggregate
// One wave per node, LINEAR fp8 512B rows (8B/lane). Batched index fetch via
// ev (no dis gathers), readlane broadcast, 8 independent row gathers per
// iter. Bias+leaky, 8B-swizzled fp8 out (feeds GEMM staging).
__global__ __launch_bounds__(256)
void agg_kernel(const u8* __restrict__ xw, const u32x2* __restrict__ ev,
                const int* __restrict__ rs, const int* __restrict__ deg,
                const float* __restrict__ dis, const float* __restrict__ bias,
                u8* __restrict__ hout, int N) {
  const int wave = threadIdx.x >> 6;
  const int lane = threadIdx.x & 63;
  const int node = blockIdx.x * 4 + wave;
  if (node >= N) return;
  const int start = rs[node];
  const int d = deg[node];
  const float dd = dis[node];
  const int fo = lane * 8;   // byte offset within 512B row

  f32x2 acc[4];
#pragma unroll
  for (int i = 0; i < 4; ++i) acc[i] = (f32x2){0.f, 0.f};

  const int total = d + 1;                      // edges + self loop
  for (int base = 0; base < total; base += 64) {
    int t = base + lane;
    int s = node;
    float w = 0.f;
    if (t < d)       { u32x2 e = ev[start + t]; s = (int)e.x; w = __builtin_bit_cast(float, e.y); }
    else if (t == d) { w = dd * dd; }           // self loop
    int cnt = total - base;
    if (cnt > 64) cnt = 64;
    int cnt8 = (cnt + 7) & ~7;
    int wi = __builtin_bit_cast(int, w);
    for (int j = 0; j < cnt8; j += 8) {
      u32x2 v[8];
      float ws[8];
#pragma unroll
      for (int k = 0; k < 8; ++k) {
        int sk = __builtin_amdgcn_readlane(s, j + k);
        ws[k] = __builtin_bit_cast(float, __builtin_amdgcn_readlane(wi, j + k));
        v[k] = *reinterpret_cast<const u32x2*>(xw + (size_t)sk * 512 + fo);
      }
#pragma unroll
      for (int k = 0; k < 8; ++k) {
        f32x2 p0 = __builtin_amdgcn_cvt_pk_f32_fp8((int)v[k].x, false);
        f32x2 p1 = __builtin_amdgcn_cvt_pk_f32_fp8((int)v[k].x, true);
        f32x2 p2 = __builtin_amdgcn_cvt_pk_f32_fp8((int)v[k].y, false);
        f32x2 p3 = __builtin_amdgcn_cvt_pk_f32_fp8((int)v[k].y, true);
        f32x2 wv = (f32x2){ws[k], ws[k]};
        acc[0] += wv * p0;
        acc[1] += wv * p1;
        acc[2] += wv * p2;
        acc[3] += wv * p3;
      }
    }
  }

  float h[8];
#pragma unroll
  for (int i = 0; i < 8; ++i) {
    float v = (i & 1) ? acc[i >> 1].y : acc[i >> 1].x;
    v += bias[fo + i];
    v = v >= 0.f ? v : 0.01f * v;
    h[i] = v;
  }
  int lo = __builtin_amdgcn_cvt_pk_fp8_f32(h[0], h[1], 0, false);
  lo = __builtin_amdgcn_cvt_pk_fp8_f32(h[2], h[3], lo, true);
  int hi = __builtin_amdgcn_cvt_pk_fp8_f32(h[4], h[5], 0, false);
  hi = __builtin_amdgcn_cvt_pk_fp8_f32(h[6], h[7], hi, true);
  u32x2 o; o.x = (u32)lo; o.y = (u32)hi;
  __builtin_nontemporal_store(o, reinterpret_cast<u32x2*>(
      hout + (size_t)node * 512 + (fo ^ ((node & 7) << 3))));
}

// L4 aggregate: LINEAR fp8 256B rows (4B/lane), ev stream, bias + leaky,
// bf16 LINEAR output (feeds pool).
__global__ __launch_bounds__(256)
void agg256_kernel(const u8* __restrict__ xw, const u32x2* __restrict__ ev,
                   const int* __restrict__ rs, const int* __restrict__ deg,
                   const float* __restrict__ dis, const float* __restrict__ bias,
                   u16* __restrict__ hout, int N) {
  const int wave = threadIdx.x >> 6;
  const int lane = threadIdx.x & 63;
  const int node = blockIdx.x * 4 + wave;
  if (node >= N) return;
  const int start = rs[node];
  const int d = deg[node];
  const float dd = dis[node];
  const int fo = lane * 4;   // byte offset within 256B row

  f32x2 acc[2];
  acc[0] = (f32x2){0.f, 0.f};
  acc[1] = (f32x2){0.f, 0.f};

  const int total = d + 1;
  for (int base = 0; base < total; base += 64) {
    int t = base + lane;
    int s = node;
    float w = 0.f;
    if (t < d)       { u32x2 e = ev[start + t]; s = (int)e.x; w = __builtin_bit_cast(float, e.y); }
    else if (t == d) { w = dd * dd; }
    int cnt = total - base;
    if (cnt > 64) cnt = 64;
    int cnt8 = (cnt + 7) & ~7;
    int wi = __builtin_bit_cast(int, w);
    for (int j = 0; j < cnt8; j += 8) {
      u32 v[8];
      float ws[8];
#pragma unroll
      for (int k = 0; k < 8; ++k) {
        int sk = __builtin_amdgcn_readlane(s, j + k);
        ws[k] = __builtin_bit_cast(float, __builtin_amdgcn_readlane(wi, j + k));
        v[k] = *reinterpret_cast<const u32*>(xw + (size_t)sk * 256 + fo);
      }
#pragma unroll
      for (int k = 0; k < 8; ++k) {
        f32x2 p0 = __builtin_amdgcn_cvt_pk_f32_fp8((int)v[k], false);
        f32x2 p1 = __builtin_amdgcn_cvt_pk_f32_fp8((int)v[k], true);
        f32x2 wv = (f32x2){ws[k], ws[k]};
        acc[0] += wv * p0;
        acc[1] += wv * p1;
      }
    }
  }

  u16x4 o;
#pragma unroll
  for (int i = 0; i < 4; ++i) {
    float v = (i & 1) ? acc[i >> 1].y : acc[i >> 1].x;
    v += bias[fo + i];
    v = v >= 0.f ? v : 0.01f * v;
    o[i] = f2bf(v);
  }
  *reinterpret_cast<u16x4*>(hout + (size_t)node * 256 + fo) = o;
}

// ---------------------------------------------------------------- pool + FC
__global__ __launch_bounds__(256) void pool_kernel(const u16* __restrict__ h,
                                                   float* __restrict__ pool, int N) {
  __shared__ float lds[8 * 256];
  const int tid = threadIdx.x;
  const int fg = tid & 31;
  const int rg = tid >> 5;
  float acc[8];
#pragma unroll
  for (int i = 0; i < 8; ++i) acc[i] = 0.f;
  for (int r = blockIdx.x * 8 + rg; r < N; r += gridDim.x * 8) {
    u16x8 v = *reinterpret_cast<const u16x8*>(h + (size_t)r * 256 + fg * 8);
#pragma unroll
    for (int i = 0; i < 8; ++i) acc[i] += bf2f(v[i]);
  }
#pragma unroll
  for (int i = 0; i < 8; ++i) lds[rg * 256 + fg * 8 + i] = acc[i];
  __syncthreads();
  float s = 0.f;
#pragma unroll
  for (int g = 0; g < 8; ++g) s += lds[g * 256 + tid];
  atomicAdd(&pool[tid], s);
}

__global__ void fc_kernel(const float* __restrict__ pool, const float* __restrict__ fcW1,
                          const float* __restrict__ fcb1, const float* __restrict__ fcW2,
                          const float* __restrict__ fcb2, float* __restrict__ out,
                          float invN) {
  int j = threadIdx.x;  // 64 threads = 1 wave
  float acc = 0.f;
  for (int f = 0; f < 256; ++f) acc += pool[f] * invN * fcW1[f * 64 + j];
  float h = acc + fcb1[j];
  h = h >= 0.f ? h : 0.01f * h;
  float p = h * fcW2[j];
  for (int o = 32; o; o >>= 1) p += __shfl_down(p, o);
  if (j == 0) out[0] = 1.f / (1.f + expf(-(p + fcb2[0])));
}

// ---------------------------------------------------------------- launch
extern "C" void kernel_launch(void* const* d_in, const int* in_sizes, int n_in,
                              void* d_out, int out_size, void* d_ws, size_t ws_size,
                              hipStream_t stream) {
  const float* x    = (const float*)d_in[0];
  const int*   ei   = (const int*)d_in[1];
  const float* W1   = (const float*)d_in[2];
  const float* b1   = (const float*)d_in[3];
  const float* W2   = (const float*)d_in[4];
  const float* b2   = (const float*)d_in[5];
  const float* W3   = (const float*)d_in[6];
  const float* b3   = (const float*)d_in[7];
  const float* W4   = (const float*)d_in[8];
  const float* b4   = (const float*)d_in[9];
  const float* fcW1 = (const float*)d_in[10];
  const float* fcb1 = (const float*)d_in[11];
  const float* fcW2 = (const float*)d_in[12];
  const float* fcb2 = (const float*)d_in[13];
  float* out = (float*)d_out;

  const int N = in_sizes[0] / 512;
  const int E = in_sizes[1] / 2;

  char* p = (char*)d_ws;
  auto carve = [&](size_t bytes) {
    char* r = p;
    p += (bytes + 255) & ~(size_t)255;
    return r;
  };
  u8*  bufX = (u8*)carve((size_t)N * 512);       // fp8: x8 (swz); h2 (swz)
  u8*  bufP = (u8*)carve((size_t)N * 512);       // fp8: xw per layer (linear)
  u8*  bufQ = (u8*)carve((size_t)N * 512);       // fp8: h1; h3 (swz)
  u16* bufH4 = (u16*)carve((size_t)N * 256 * 2); // bf16 linear h4 for pool
  u8* Wt1 = (u8*)carve(512 * 512);
  u8* Wt2 = (u8*)carve(512 * 512);
  u8* Wt3 = (u8*)carve(512 * 512);
  u8* Wt4 = (u8*)carve(512 * 256);
  int* deg    = (int*)carve((size_t)N * 4);
  int* cursor = (int*)carve((size_t)N * 4);
  int* rs     = (int*)carve((size_t)(N + 1) * 4);
  u32x2* ev   = (u32x2*)carve((size_t)E * 8);
  int* bsum   = (int*)carve(1024 * 4);
  int* boff   = (int*)carve(1024 * 4);
  int* flag   = (int*)carve(256);
  float* disv = (float*)carve((size_t)N * 4);
  float* pool = (float*)carve(256 * 4);
  if ((size_t)(p - (char*)d_ws) > ws_size) return;  // need ~240 MB

  const int nb1024 = (N + 1023) / 1024;

  init_kernel<<<(N + 255) / 256, 256, 0, stream>>>(deg, cursor, pool, N);
  detect_kernel<<<1, 256, 0, stream>>>(ei, flag);
  degree_kernel<<<(E + 255) / 256, 256, 0, stream>>>(ei, flag, deg, E);
  dis_kernel<<<(N + 255) / 256, 256, 0, stream>>>(deg, disv, N);
  scan1_kernel<<<nb1024, 1024, 0, stream>>>(deg, rs, bsum, N);
  scan2_kernel<<<1, 1024, 0, stream>>>(bsum, boff, nb1024);
  scan3_kernel<<<(N + 255) / 256, 256, 0, stream>>>(rs, boff, N);
  fill_kernel<<<(E + 255) / 256, 256, 0, stream>>>(ei, flag, rs, cursor, disv, ev, E);

  convx_kernel<<<((size_t)N * 512 / 4 + 255) / 256, 256, 0, stream>>>(x, bufX, (size_t)N * 512);
  convw_kernel<<<(512 * 512 + 255) / 256, 256, 0, stream>>>(W1, Wt1, 512);
  convw_kernel<<<(512 * 512 + 255) / 256, 256, 0, stream>>>(W2, Wt2, 512);
  convw_kernel<<<(512 * 512 + 255) / 256, 256, 0, stream>>>(W3, Wt3, 512);
  convw_kernel<<<(512 * 256 + 255) / 256, 256, 0, stream>>>(W4, Wt4, 256);

  const int gm = (N + 127) / 128;
  const int gm8 = (gm + 7) & ~7;
  const unsigned ga = (unsigned)((N + 3) / 4);

  // L1: xw1 = x8@W1 ; h1 = leaky(agg xw1 + b1)
  gemm8_kernel<<<gm8 * 4, 256, 0, stream>>>(bufX, Wt1, bufP, N, 512, gm, 2);
  agg_kernel<<<ga, 256, 0, stream>>>(bufP, ev, rs, deg, disv, b1, bufQ, N);
  // L2
  gemm8_kernel<<<gm8 * 4, 256, 0, stream>>>(bufQ, Wt2, bufP, N, 512, gm, 2);
  agg_kernel<<<ga, 256, 0, stream>>>(bufP, ev, rs, deg, disv, b2, bufX, N);
  // L3
  gemm8_kernel<<<gm8 * 4, 256, 0, stream>>>(bufX, Wt3, bufP, N, 512, gm, 2);
  agg_kernel<<<ga, 256, 0, stream>>>(bufP, ev, rs, deg, disv, b3, bufQ, N);
  // L4 (linearity): xw4 = h3@W4 (256-wide fp8 linear) ; h4 = leaky(agg xw4 + b4)
  gemm8_kernel<<<gm8 * 2, 256, 0, stream>>>(bufQ, Wt4, bufP, N, 256, gm, 1);
  agg256_kernel<<<ga, 256, 0, stream>>>(bufP, ev, rs, deg, disv, b4, bufH4, N);

  pool_kernel<<<256, 256, 0, stream>>>(bufH4, pool, N);
  fc_kernel<<<1, 64, 0, stream>>>(pool, fcW1, fcb1, fcW2, fcb2, out, 1.0f / (float)N);
}